// Round 14
// baseline (35.598 us; speedup 1.0000x reference)
//
#include <hip/hip_runtime.h>

#define DEV __device__ __forceinline__

typedef float af4 __attribute__((ext_vector_type(4), aligned(4)));

DEV float silu_f(float v) { return v / (1.0f + __expf(-v)); }

// Cox-de Boor closed form (order 3) for stage 4.
DEV int bspline4(float x, float g0, float inv_h, int imax, float w[4]) {
  float t = (x - g0) * inv_h;
  float fi = floorf(t);
  int i = (int)fi;
  if (t < 0.0f || i > imax) { w[0] = w[1] = w[2] = w[3] = 0.0f; return 0; }
  float u = t - fi;
  float u2 = u * u, u3 = u2 * u;
  float om = 1.0f - u;
  const float c6 = 1.0f / 6.0f;
  w[0] = om * om * om * c6;
  w[1] = (3.0f * u3 - 6.0f * u2 + 4.0f) * c6;
  w[2] = (-3.0f * u3 + 3.0f * u2 + 3.0f * u + 1.0f) * c6;
  w[3] = u3 * c6;
  return i - 3;
}

// Exact per-interval cubic coefficients of the uniform cubic B-spline combo.
DEV float4 cubic_coeffs(float s0, float s1, float s2, float s3) {
  float4 c;
  const float c6 = 1.0f / 6.0f;
  c.x = (s0 + 4.0f * s1 + s2) * c6;
  c.y = (s2 - s0) * 0.5f;
  c.z = (s0 - 2.0f * s1 + s2) * 0.5f;
  c.w = (s3 - s0 + 3.0f * (s1 - s2)) * c6;
  return c;
}

// Pack (interval, frac) into one float: e = t if in-range else zeroSlot+0.5.
DEV float enc_interval(float v, float g0, float inv_h, float tmax, float zslot) {
  const float t = (v - g0) * inv_h;
  return (t >= 0.0f && t < tmax) ? t : zslot;
}

// ---------------- Setup kernel: build both coeff tables into d_ws ----------
// tabg[0..539]    = tab1: idx = tap*60 + k*12 + iv   (iv 11 = zeros)
// tabg[540..1304] = tab2: idx = tap*85 + k*17 + iv   (iv 16 = zeros)
// Same arithmetic as the previous in-kernel build (bit-identical tables).
__global__ __launch_bounds__(256) void kkan_setup(
    const float* __restrict__ c1s, const float* __restrict__ c1sc,
    const float* __restrict__ c2s, const float* __restrict__ c2sc,
    float4* __restrict__ tabg)
{
  const int gid = blockIdx.x * 256 + threadIdx.x;
  if (gid < 540) {
    const int tap = gid / 60, rem = gid % 60;
    const int k = rem / 12, iv = rem % 12;
    float4 c = make_float4(0.f, 0.f, 0.f, 0.f);
    if (iv <= 10) {
      const float sc = c1sc[k * 9 + tap];
      const float* swp = &c1s[(k * 9 + tap) * 8];
      float s[4];
      #pragma unroll
      for (int j = 0; j < 4; ++j) {
        const int m = iv - 3 + j;
        s[j] = ((unsigned)m < 8u) ? swp[m] * sc : 0.f;
      }
      c = cubic_coeffs(s[0], s[1], s[2], s[3]);
    }
    tabg[gid] = c;
  } else if (gid < 1305) {
    const int idx = gid - 540;
    const int tap = idx / 85, rem = idx % 85;
    const int k = rem / 17, iv = rem % 17;
    float4 c = make_float4(0.f, 0.f, 0.f, 0.f);
    if (iv <= 15) {
      const float sc = c2sc[k * 9 + tap];
      const float* swp = &c2s[(k * 9 + tap) * 13];
      float s[4];
      #pragma unroll
      for (int j = 0; j < 4; ++j) {
        const int m = iv - 3 + j;
        s[j] = ((unsigned)m < 13u) ? swp[m] * sc : 0.f;
      }
      c = cubic_coeffs(s[0], s[1], s[2], s[3]);
    }
    tabg[gid] = c;
  }
}

// ---------------- Main kernel: one block (512 thr) per sample --------------
// R13/R10 structure (verified 32.5 us / absmax 0); the only change is that
// the coeff tables are COPIED (coalesced b128) from d_ws instead of rebuilt
// per block (which cost div/mod VALU + ~6.5K scattered L2 gathers per block).
// conv1 grid: g0=-2.2 h=0.4 imax=10 / conv2: g0=-1.6 h=0.2 imax=15
// kan1 grid: g0=-0.3 h=0.1 imax=15
__global__ __launch_bounds__(512, 8) void kkan_fused(
    const float* __restrict__ x,
    const float* __restrict__ c1b, const float* __restrict__ c2b,
    const float* __restrict__ kb,  const float* __restrict__ ks,
    const float* __restrict__ ksc,
    const float4* __restrict__ tabg,
    float* __restrict__ out)
{
  __shared__ float4 tabs[1305];   // [0..539]=tab1, [540..1304]=tab2
  __shared__ float2 pre1[784];    // per input pixel (silu, e) on conv1 grid
  __shared__ float2 pre2[845];    // per pooled-conv1 value (silu, e) on conv2 grid
  __shared__ float  fv[625];      // pooled conv2, layout (c*5+k)*25 + y*5+x
  __shared__ float  lred[8][10];
  __shared__ float  lfin[10];

  const float4* tab1 = tabs;
  const float4* tab2 = tabs + 540;

  const int b = blockIdx.x;
  const int tid = threadIdx.x;

  // ---- Stage 0: input precomp + table copy (coalesced) ----
  const float4* xb4 = (const float4*)(x + b * 784);  // 784 % 4 == 0
  #pragma unroll 1
  for (int i = tid; i < 196; i += 512) {
    const float4 v4 = xb4[i];
    const float vs[4] = {v4.x, v4.y, v4.z, v4.w};
    #pragma unroll
    for (int j = 0; j < 4; ++j) {
      const float v = vs[j];
      pre1[i * 4 + j] = make_float2(silu_f(v),
                                    enc_interval(v, -2.2f, 2.5f, 11.0f, 11.5f));
    }
  }
  #pragma unroll 1
  for (int i = tid; i < 1305; i += 512) tabs[i] = tabg[i];
  __syncthreads();

  // ---- Stage 1: conv1 + 2x2 pool. item = pool_pos*4 + quadrant ----
  #pragma unroll 1
  for (int q = tid; q < 676; q += 512) {
    const int pos = q >> 2, quad = q & 3;
    const int pi = pos / 13, pj = pos % 13;
    const int oh = 2 * pi + (quad >> 1), ow = 2 * pj + (quad & 1);
    float acc[5] = {0.f, 0.f, 0.f, 0.f, 0.f};
    #pragma unroll 1
    for (int kh = 0; kh < 3; ++kh) {
      #pragma unroll 1
      for (int kw = 0; kw < 3; ++kw) {
        const int tap = kh * 3 + kw;
        const float2 pc = pre1[(oh + kh) * 28 + (ow + kw)];
        const float sil = pc.x;
        const float fi = floorf(pc.y);
        const int ic = (int)fi;
        const float u = pc.y - fi;
        const float4* tp = &tab1[tap * 60 + ic];
        const float* bw = &c1b[tap];  // wave-uniform -> s_load
        #pragma unroll
        for (int k = 0; k < 5; ++k) {
          const float4 c = tp[k * 12];
          const float sp = ((c.w * u + c.z) * u + c.y) * u + c.x;
          acc[k] += sil * bw[k * 9] + sp;
        }
      }
    }
    #pragma unroll
    for (int k = 0; k < 5; ++k) {
      float m = acc[k];
      m = fmaxf(m, __shfl_xor(m, 1));
      m = fmaxf(m, __shfl_xor(m, 2));
      if (quad == 0) {
        pre2[(k * 13 + pi) * 13 + pj] =
            make_float2(silu_f(m), enc_interval(m, -1.6f, 5.0f, 16.0f, 16.5f));
      }
    }
  }
  __syncthreads();

  // ---- Stage 2: conv2 + 2x2 pool fused ----
  if (tid < 500) {
    const int pos = tid >> 2, quad = tid & 3;
    const int c = pos / 25, rr = pos % 25;
    const int y = rr / 5, xx = rr % 5;
    const int oh = 2 * y + (quad >> 1), ow = 2 * xx + (quad & 1);
    float acc[5] = {0.f, 0.f, 0.f, 0.f, 0.f};
    #pragma unroll 1
    for (int kh = 0; kh < 3; ++kh) {
      #pragma unroll 1
      for (int kw = 0; kw < 3; ++kw) {
        const int tap = kh * 3 + kw;
        const float2 pc = pre2[(c * 13 + oh + kh) * 13 + (ow + kw)];
        const float sil = pc.x;
        const float fi = floorf(pc.y);
        const int ic = (int)fi;
        const float u = pc.y - fi;
        const float4* tp = &tab2[tap * 85 + ic];
        const float* bw = &c2b[tap];  // wave-uniform -> s_load
        #pragma unroll
        for (int k = 0; k < 5; ++k) {
          const float4 cc = tp[k * 17];
          const float sp = ((cc.w * u + cc.z) * u + cc.y) * u + cc.x;
          acc[k] += sil * bw[k * 9] + sp;
        }
      }
    }
    #pragma unroll
    for (int k = 0; k < 5; ++k) {
      float m = acc[k];
      m = fmaxf(m, __shfl_xor(m, 1));
      m = fmaxf(m, __shfl_xor(m, 2));
      if (quad == 0) fv[(c * 5 + k) * 25 + rr] = m;
    }
  }
  __syncthreads();

  // ---- Stage 4: KANLinear 625->10, one b128 gather per (i,o) ----
  float acc[10] = {0.f, 0.f, 0.f, 0.f, 0.f, 0.f, 0.f, 0.f, 0.f, 0.f};
  #pragma unroll 1
  for (int i = tid; i < 625; i += 512) {
    const float v = fv[i];
    const float sil = silu_f(v);
    float w[4];
    const int m0 = bspline4(v, -0.3f, 10.0f, 15, w);
    const int mb = min(max(m0, 0), 9);
    const int d = m0 - mb;  // in [-3, 3]
    float w2[4];
    #pragma unroll
    for (int t = 0; t < 4; ++t) {
      const int j = t - d;
      float r = 0.f;
      r = (j == 0) ? w[0] : r;
      r = (j == 1) ? w[1] : r;
      r = (j == 2) ? w[2] : r;
      r = (j == 3) ? w[3] : r;
      w2[t] = r;
    }
    const int gidx = i * 13 + mb;
    #pragma unroll 5
    for (int o = 0; o < 10; ++o) {
      const af4 g = *reinterpret_cast<const af4*>(ks + o * 8125 + gidx);
      const float s = w2[0] * g.x + w2[1] * g.y + w2[2] * g.z + w2[3] * g.w;
      acc[o] += sil * kb[o * 625 + i] + s * ksc[o * 625 + i];
    }
  }
  #pragma unroll
  for (int o = 0; o < 10; ++o) {
    float v = acc[o];
    for (int off = 32; off > 0; off >>= 1) v += __shfl_down(v, off);
    acc[o] = v;
  }
  const int wave = tid >> 6, lane = tid & 63;
  if (lane == 0) {
    #pragma unroll
    for (int o = 0; o < 10; ++o) lred[wave][o] = acc[o];
  }
  __syncthreads();
  if (tid < 10) {
    float s = 0.f;
    #pragma unroll
    for (int wv = 0; wv < 8; ++wv) s += lred[wv][tid];
    lfin[tid] = s;
  }
  __syncthreads();
  if (tid == 0) {
    float mx = lfin[0];
    #pragma unroll
    for (int o = 1; o < 10; ++o) mx = fmaxf(mx, lfin[o]);
    float s = 0.f;
    #pragma unroll
    for (int o = 0; o < 10; ++o) s += __expf(lfin[o] - mx);
    const float ls = logf(s) + mx;
    #pragma unroll
    for (int o = 0; o < 10; ++o) out[b * 10 + o] = lfin[o] - ls;
  }
}

extern "C" void kernel_launch(void* const* d_in, const int* in_sizes, int n_in,
                              void* d_out, int out_size, void* d_ws, size_t ws_size,
                              hipStream_t stream) {
  (void)n_in; (void)ws_size; (void)out_size;
  const float* x    = (const float*)d_in[0];
  const float* c1b  = (const float*)d_in[1];
  const float* c1s  = (const float*)d_in[2];
  const float* c1sc = (const float*)d_in[3];
  const float* c2b  = (const float*)d_in[4];
  const float* c2s  = (const float*)d_in[5];
  const float* c2sc = (const float*)d_in[6];
  const float* kb   = (const float*)d_in[7];
  const float* ks   = (const float*)d_in[8];
  const float* ksc  = (const float*)d_in[9];
  float* out = (float*)d_out;

  float4* tabg = (float4*)d_ws;  // 1305 float4 = 20880 B

  kkan_setup<<<dim3(6), dim3(256), 0, stream>>>(c1s, c1sc, c2s, c2sc, tabg);

  const int B = in_sizes[0] / 784;
  kkan_fused<<<dim3(B), dim3(512), 0, stream>>>(
      x, c1b, c2b, kb, ks, ksc, tabg, out);
}

// Round 15
// 32.422 us; speedup vs baseline: 1.0979x; 1.0979x over previous
//
#include <hip/hip_runtime.h>

#define DEV __device__ __forceinline__

typedef float af4 __attribute__((ext_vector_type(4), aligned(4)));

DEV float silu_f(float v) { return v / (1.0f + __expf(-v)); }

// Cox-de Boor closed form (order 3) for stage 4.
DEV int bspline4(float x, float g0, float inv_h, int imax, float w[4]) {
  float t = (x - g0) * inv_h;
  float fi = floorf(t);
  int i = (int)fi;
  if (t < 0.0f || i > imax) { w[0] = w[1] = w[2] = w[3] = 0.0f; return 0; }
  float u = t - fi;
  float u2 = u * u, u3 = u2 * u;
  float om = 1.0f - u;
  const float c6 = 1.0f / 6.0f;
  w[0] = om * om * om * c6;
  w[1] = (3.0f * u3 - 6.0f * u2 + 4.0f) * c6;
  w[2] = (-3.0f * u3 + 3.0f * u2 + 3.0f * u + 1.0f) * c6;
  w[3] = u3 * c6;
  return i - 3;
}

// Exact per-interval cubic coefficients of the uniform cubic B-spline combo.
DEV float4 cubic_coeffs(float s0, float s1, float s2, float s3) {
  float4 c;
  const float c6 = 1.0f / 6.0f;
  c.x = (s0 + 4.0f * s1 + s2) * c6;
  c.y = (s2 - s0) * 0.5f;
  c.z = (s0 - 2.0f * s1 + s2) * 0.5f;
  c.w = (s3 - s0 + 3.0f * (s1 - s2)) * c6;
  return c;
}

// Pack (interval, frac) into one float: e = t if in-range else zeroSlot+0.5.
DEV float enc_interval(float v, float g0, float inv_h, float tmax, float zslot) {
  const float t = (v - g0) * inv_h;
  return (t >= 0.0f && t < tmax) ? t : zslot;
}

// One block (512 thr) per sample; whole net in LDS.  (Best verified kernel:
// 32.5 us, absmax 0, reproduced twice. Structure: per-pixel (silu,e) precomp;
// per-interval cubic Horner tables in LDS; fused conv+pool with quadrant
// shuffle-max; stage-4 window-clamped single-b128 gather per (i,o).)
// conv1 grid: g0=-2.2 h=0.4 imax=10 (12 slots, slot 11 zeros)
// conv2 grid: g0=-1.6 h=0.2 imax=15 (17 slots, slot 16 zeros)
// kan1  grid: g0=-0.3 h=0.1 imax=15
__global__ __launch_bounds__(512, 8) void kkan_fused(
    const float* __restrict__ x,
    const float* __restrict__ c1b, const float* __restrict__ c1s, const float* __restrict__ c1sc,
    const float* __restrict__ c2b, const float* __restrict__ c2s, const float* __restrict__ c2sc,
    const float* __restrict__ kb,  const float* __restrict__ ks,  const float* __restrict__ ksc,
    float* __restrict__ out)
{
  __shared__ float4 tab1[540];    // [tap][k][interval 12] cubic coeffs
  __shared__ float4 tab2[765];    // [tap][k][interval 17]
  __shared__ float2 pre1[784];    // per input pixel (silu, e) on conv1 grid
  __shared__ float2 pre2[845];    // per pooled-conv1 value (silu, e) on conv2 grid
  __shared__ float  fv[625];      // pooled conv2, layout (c*5+k)*25 + y*5+x
  __shared__ float  lred[8][10];
  __shared__ float  lfin[10];

  const int b = blockIdx.x;
  const int tid = threadIdx.x;

  // ---- Stage 0: input precomp + both coeff tables ----
  const float4* xb4 = (const float4*)(x + b * 784);  // 784 % 4 == 0
  #pragma unroll 1
  for (int i = tid; i < 196; i += 512) {
    const float4 v4 = xb4[i];
    const float vs[4] = {v4.x, v4.y, v4.z, v4.w};
    #pragma unroll
    for (int j = 0; j < 4; ++j) {
      const float v = vs[j];
      pre1[i * 4 + j] = make_float2(silu_f(v),
                                    enc_interval(v, -2.2f, 2.5f, 11.0f, 11.5f));
    }
  }
  #pragma unroll 1
  for (int idx = tid; idx < 540; idx += 512) {
    const int tap = idx / 60, rem = idx % 60;
    const int k = rem / 12, iv = rem % 12;
    float4 c = make_float4(0.f, 0.f, 0.f, 0.f);
    if (iv <= 10) {
      const float sc = c1sc[k * 9 + tap];
      const float* swp = &c1s[(k * 9 + tap) * 8];
      float s[4];
      #pragma unroll
      for (int j = 0; j < 4; ++j) {
        const int m = iv - 3 + j;
        s[j] = ((unsigned)m < 8u) ? swp[m] * sc : 0.f;
      }
      c = cubic_coeffs(s[0], s[1], s[2], s[3]);
    }
    tab1[idx] = c;
  }
  #pragma unroll 1
  for (int idx = tid; idx < 765; idx += 512) {
    const int tap = idx / 85, rem = idx % 85;
    const int k = rem / 17, iv = rem % 17;
    float4 c = make_float4(0.f, 0.f, 0.f, 0.f);
    if (iv <= 15) {
      const float sc = c2sc[k * 9 + tap];
      const float* swp = &c2s[(k * 9 + tap) * 13];
      float s[4];
      #pragma unroll
      for (int j = 0; j < 4; ++j) {
        const int m = iv - 3 + j;
        s[j] = ((unsigned)m < 13u) ? swp[m] * sc : 0.f;
      }
      c = cubic_coeffs(s[0], s[1], s[2], s[3]);
    }
    tab2[idx] = c;
  }
  __syncthreads();

  // ---- Stage 1: conv1 + 2x2 pool. item = pool_pos*4 + quadrant ----
  #pragma unroll 1
  for (int q = tid; q < 676; q += 512) {
    const int pos = q >> 2, quad = q & 3;
    const int pi = pos / 13, pj = pos % 13;
    const int oh = 2 * pi + (quad >> 1), ow = 2 * pj + (quad & 1);
    float acc[5] = {0.f, 0.f, 0.f, 0.f, 0.f};
    #pragma unroll 1
    for (int kh = 0; kh < 3; ++kh) {
      #pragma unroll 1
      for (int kw = 0; kw < 3; ++kw) {
        const int tap = kh * 3 + kw;
        const float2 pc = pre1[(oh + kh) * 28 + (ow + kw)];
        const float sil = pc.x;
        const float fi = floorf(pc.y);
        const int ic = (int)fi;
        const float u = pc.y - fi;
        const float4* tp = &tab1[tap * 60 + ic];
        const float* bw = &c1b[tap];  // wave-uniform -> s_load
        #pragma unroll
        for (int k = 0; k < 5; ++k) {
          const float4 c = tp[k * 12];
          const float sp = ((c.w * u + c.z) * u + c.y) * u + c.x;
          acc[k] += sil * bw[k * 9] + sp;
        }
      }
    }
    #pragma unroll
    for (int k = 0; k < 5; ++k) {
      float m = acc[k];
      m = fmaxf(m, __shfl_xor(m, 1));
      m = fmaxf(m, __shfl_xor(m, 2));
      if (quad == 0) {
        pre2[(k * 13 + pi) * 13 + pj] =
            make_float2(silu_f(m), enc_interval(m, -1.6f, 5.0f, 16.0f, 16.5f));
      }
    }
  }
  __syncthreads();

  // ---- Stage 2: conv2 + 2x2 pool fused ----
  if (tid < 500) {
    const int pos = tid >> 2, quad = tid & 3;
    const int c = pos / 25, rr = pos % 25;
    const int y = rr / 5, xx = rr % 5;
    const int oh = 2 * y + (quad >> 1), ow = 2 * xx + (quad & 1);
    float acc[5] = {0.f, 0.f, 0.f, 0.f, 0.f};
    #pragma unroll 1
    for (int kh = 0; kh < 3; ++kh) {
      #pragma unroll 1
      for (int kw = 0; kw < 3; ++kw) {
        const int tap = kh * 3 + kw;
        const float2 pc = pre2[(c * 13 + oh + kh) * 13 + (ow + kw)];
        const float sil = pc.x;
        const float fi = floorf(pc.y);
        const int ic = (int)fi;
        const float u = pc.y - fi;
        const float4* tp = &tab2[tap * 85 + ic];
        const float* bw = &c2b[tap];  // wave-uniform -> s_load
        #pragma unroll
        for (int k = 0; k < 5; ++k) {
          const float4 cc = tp[k * 17];
          const float sp = ((cc.w * u + cc.z) * u + cc.y) * u + cc.x;
          acc[k] += sil * bw[k * 9] + sp;
        }
      }
    }
    #pragma unroll
    for (int k = 0; k < 5; ++k) {
      float m = acc[k];
      m = fmaxf(m, __shfl_xor(m, 1));
      m = fmaxf(m, __shfl_xor(m, 2));
      if (quad == 0) fv[(c * 5 + k) * 25 + rr] = m;
    }
  }
  __syncthreads();

  // ---- Stage 4: KANLinear 625->10, one b128 gather per (i,o) ----
  float acc[10] = {0.f, 0.f, 0.f, 0.f, 0.f, 0.f, 0.f, 0.f, 0.f, 0.f};
  #pragma unroll 1
  for (int i = tid; i < 625; i += 512) {
    const float v = fv[i];
    const float sil = silu_f(v);
    float w[4];
    const int m0 = bspline4(v, -0.3f, 10.0f, 15, w);
    const int mb = min(max(m0, 0), 9);
    const int d = m0 - mb;  // in [-3, 3]
    float w2[4];
    #pragma unroll
    for (int t = 0; t < 4; ++t) {
      const int j = t - d;
      float r = 0.f;
      r = (j == 0) ? w[0] : r;
      r = (j == 1) ? w[1] : r;
      r = (j == 2) ? w[2] : r;
      r = (j == 3) ? w[3] : r;
      w2[t] = r;
    }
    const int gidx = i * 13 + mb;
    #pragma unroll 5
    for (int o = 0; o < 10; ++o) {
      const af4 g = *reinterpret_cast<const af4*>(ks + o * 8125 + gidx);
      const float s = w2[0] * g.x + w2[1] * g.y + w2[2] * g.z + w2[3] * g.w;
      acc[o] += sil * kb[o * 625 + i] + s * ksc[o * 625 + i];
    }
  }
  #pragma unroll
  for (int o = 0; o < 10; ++o) {
    float v = acc[o];
    for (int off = 32; off > 0; off >>= 1) v += __shfl_down(v, off);
    acc[o] = v;
  }
  const int wave = tid >> 6, lane = tid & 63;
  if (lane == 0) {
    #pragma unroll
    for (int o = 0; o < 10; ++o) lred[wave][o] = acc[o];
  }
  __syncthreads();
  if (tid < 10) {
    float s = 0.f;
    #pragma unroll
    for (int wv = 0; wv < 8; ++wv) s += lred[wv][tid];
    lfin[tid] = s;
  }
  __syncthreads();
  if (tid == 0) {
    float mx = lfin[0];
    #pragma unroll
    for (int o = 1; o < 10; ++o) mx = fmaxf(mx, lfin[o]);
    float s = 0.f;
    #pragma unroll
    for (int o = 0; o < 10; ++o) s += __expf(lfin[o] - mx);
    const float ls = logf(s) + mx;
    #pragma unroll
    for (int o = 0; o < 10; ++o) out[b * 10 + o] = lfin[o] - ls;
  }
}

extern "C" void kernel_launch(void* const* d_in, const int* in_sizes, int n_in,
                              void* d_out, int out_size, void* d_ws, size_t ws_size,
                              hipStream_t stream) {
  (void)n_in; (void)d_ws; (void)ws_size; (void)out_size;
  const float* x    = (const float*)d_in[0];
  const float* c1b  = (const float*)d_in[1];
  const float* c1s  = (const float*)d_in[2];
  const float* c1sc = (const float*)d_in[3];
  const float* c2b  = (const float*)d_in[4];
  const float* c2s  = (const float*)d_in[5];
  const float* c2sc = (const float*)d_in[6];
  const float* kb   = (const float*)d_in[7];
  const float* ks   = (const float*)d_in[8];
  const float* ksc  = (const float*)d_in[9];
  float* out = (float*)d_out;

  const int B = in_sizes[0] / 784;
  kkan_fused<<<dim3(B), dim3(512), 0, stream>>>(
      x, c1b, c1s, c1sc, c2b, c2s, c2sc, kb, ks, ksc, out);
}